// Round 7
// baseline (770.261 us; speedup 1.0000x reference)
//
#include <hip/hip_runtime.h>
#include <hip/hip_bf16.h>

// Problem constants (fixed by the reference file).
#define K_OFF 27
#define M_PTS 100000
#define C_CH 64
#define N_OUT_PTS 400000
#define BN_EPS 1e-5f
#define BATCHES 25     // 16-pt MFMA batches per wave
#define WAVES_PB 2     // block = 128 threads
#define BLK_X 125      // 125 blocks * 2 waves * 25 batches * 16 pts = 100000

typedef short short8 __attribute__((ext_vector_type(8)));
typedef float floatx4 __attribute__((ext_vector_type(4)));

// Packed 2xbf16 atomic add (exists on gfx950; packed fp32 does NOT - r5).
__device__ inline void pk_atomic_add_bf16(__hip_bfloat16* p, int bits) {
    asm volatile("global_atomic_pk_add_bf16 %0, %1, off"
                 :: "v"((unsigned long long)p), "v"(bits) : "memory");
}

__device__ inline int pack_bf16(float a, float b) {
    union { __hip_bfloat162 h; int i; } cv;
    cv.h = __hip_bfloat162(__float2bfloat16(a), __float2bfloat16(b));
    return cv.i;
}

// ---------------------------------------------------------------------------
// Kernel 1: gather -> 16x64 @ 64x64 MFMA -> scatter-add (packed bf16 atomics).
// Per wave-batch: 16 points. A = gathered x rows (16x64, bf16 via LDS with
// 16B-chunk XOR swizzle), B = W[k] as 8 register-resident MFMA fragments
// (loaded once per wave, amortized over 25 batches). 8 x mfma_f32_16x16x32.
// C layout (verified, m89/m91): col=lane&15 (out ch within tile),
// row=(lane>>4)*4+reg (point). Scatter: ch pairs via shfl_xor(1), lanes
// split even->tiles 0,1 / odd->tiles 2,3; 32 pk-atomic dwords per point.
// This removes round-6's ~160 cyc/pt AGPR-copy VALU tax (VALUBusy 64%).
// ---------------------------------------------------------------------------
__global__ __launch_bounds__(128, 4) void scatter_gemm(
    const float* __restrict__ x, const float* __restrict__ W,
    const int* __restrict__ in_idx, const int* __restrict__ out_idx,
    __hip_bfloat16* __restrict__ out_ws)
{
    const int k = blockIdx.y;
    const int lane = threadIdx.x & 63;
    const int wv = __builtin_amdgcn_readfirstlane(threadIdx.x >> 6);
    const int m = lane & 15;        // point-row within batch / B col
    const int quad = lane >> 4;     // k-group

    __shared__ int4 lds_raw[WAVES_PB * 128];            // 2 KB per wave
    char* lds = (char*)(lds_raw + wv * 128);

    const float* __restrict__ Wk = W + (size_t)k * C_CH * C_CH;

    // B fragments: bfrag[h][t] holds B[k=h*32+quad*8+j][n=t*16+m], j=0..7.
    short8 bfrag[2][4];
    #pragma unroll
    for (int h = 0; h < 2; ++h) {
        #pragma unroll
        for (int t = 0; t < 4; ++t) {
            union { short8 s; int i4[4]; } u;
            #pragma unroll
            for (int jj = 0; jj < 4; ++jj) {
                float w0 = Wk[(h * 32 + quad * 8 + 2 * jj)     * C_CH + t * 16 + m];
                float w1 = Wk[(h * 32 + quad * 8 + 2 * jj + 1) * C_CH + t * 16 + m];
                u.i4[jj] = pack_bf16(w0, w1);
            }
            bfrag[h][t] = u.s;
        }
    }

    int base = k * M_PTS + (blockIdx.x * WAVES_PB + wv) * (BATCHES * 16);

    for (int bt = 0; bt < BATCHES; ++bt, base += 16) {
        // lane's point-row is m: per-lane indices, one dword load each.
        const int vsrc = in_idx[base + m];
        const int vdst = out_idx[base + m];

        // Gather: lane loads 16 floats of row m, segment quad (4 x float4).
        const float4* xr = (const float4*)(x + (size_t)vsrc * C_CH + quad * 16);
        float4 g0 = xr[0], g1 = xr[1], g2 = xr[2], g3 = xr[3];

        // fp32 -> bf16, two 16B chunks.
        int4 c0, c1;
        c0.x = pack_bf16(g0.x, g0.y); c0.y = pack_bf16(g0.z, g0.w);
        c0.z = pack_bf16(g1.x, g1.y); c0.w = pack_bf16(g1.z, g1.w);
        c1.x = pack_bf16(g2.x, g2.y); c1.y = pack_bf16(g2.z, g2.w);
        c1.z = pack_bf16(g3.x, g3.y); c1.w = pack_bf16(g3.z, g3.w);

        // Stage into LDS A-tile: row m = 128 B = 8 chunks, chunk c stored at
        // position c ^ (m&7) (kills the 16-way stride-128 bank conflict).
        int4* row = (int4*)(lds + m * 128);
        row[(2 * quad)     ^ (m & 7)] = c0;
        row[(2 * quad + 1) ^ (m & 7)] = c1;

        // A-fragments: lane holds A[m][k=h*32+quad*8+j] -> chunk h*4+quad.
        short8 a0 = *(short8*)(lds + m * 128 + (((0 << 2) | quad) ^ (m & 7)) * 16);
        short8 a1 = *(short8*)(lds + m * 128 + (((1 << 2) | quad) ^ (m & 7)) * 16);

        floatx4 acc0 = {0.f, 0.f, 0.f, 0.f}, acc1 = acc0, acc2 = acc0, acc3 = acc0;
        acc0 = __builtin_amdgcn_mfma_f32_16x16x32_bf16(a0, bfrag[0][0], acc0, 0, 0, 0);
        acc1 = __builtin_amdgcn_mfma_f32_16x16x32_bf16(a0, bfrag[0][1], acc1, 0, 0, 0);
        acc2 = __builtin_amdgcn_mfma_f32_16x16x32_bf16(a0, bfrag[0][2], acc2, 0, 0, 0);
        acc3 = __builtin_amdgcn_mfma_f32_16x16x32_bf16(a0, bfrag[0][3], acc3, 0, 0, 0);
        acc0 = __builtin_amdgcn_mfma_f32_16x16x32_bf16(a1, bfrag[1][0], acc0, 0, 0, 0);
        acc1 = __builtin_amdgcn_mfma_f32_16x16x32_bf16(a1, bfrag[1][1], acc1, 0, 0, 0);
        acc2 = __builtin_amdgcn_mfma_f32_16x16x32_bf16(a1, bfrag[1][2], acc2, 0, 0, 0);
        acc3 = __builtin_amdgcn_mfma_f32_16x16x32_bf16(a1, bfrag[1][3], acc3, 0, 0, 0);

        // Scatter C. Value (row r', ch t*16+m) lives in acc{t}[r] of lane
        // with quad=r'>>2, reg r=r'&3. Pair channels via shfl_xor(1).
        #pragma unroll
        for (int r = 0; r < 4; ++r) {
            int drow = __shfl(vdst, quad * 4 + r);
            __hip_bfloat16* rp = out_ws + (size_t)drow * C_CH + (m & ~1);
            float v0 = acc0[r], v1 = acc1[r], v2 = acc2[r], v3 = acc3[r];
            float o0 = __shfl_xor(v0, 1), o1 = __shfl_xor(v1, 1);
            float o2 = __shfl_xor(v2, 1), o3 = __shfl_xor(v3, 1);
            if ((lane & 1) == 0) {          // even ch lane: tiles 0,1
                pk_atomic_add_bf16(rp +  0, pack_bf16(v0, o0));
                pk_atomic_add_bf16(rp + 16, pack_bf16(v1, o1));
            } else {                        // odd ch lane: tiles 2,3
                pk_atomic_add_bf16(rp + 32, pack_bf16(o2, v2));
                pk_atomic_add_bf16(rp + 48, pack_bf16(o3, v3));
            }
        }
    }
}

// ---------------------------------------------------------------------------
// Kernel 2: per-channel sum / sumsq over bf16 accumulator (uint4 = 8 bf16).
// ---------------------------------------------------------------------------
__global__ __launch_bounds__(256) void bn_stats(
    const __hip_bfloat16* __restrict__ ws, float* __restrict__ stats)
{
    const uint4* in = (const uint4*)ws;
    const size_t n = (size_t)N_OUT_PTS * C_CH / 8;
    const size_t stride = (size_t)gridDim.x * blockDim.x;
    float s[8], s2[8];
    #pragma unroll
    for (int j = 0; j < 8; ++j) { s[j] = 0.f; s2[j] = 0.f; }
    for (size_t i = (size_t)blockIdx.x * blockDim.x + threadIdx.x; i < n; i += stride) {
        uint4 q = in[i];
        unsigned wds[4] = {q.x, q.y, q.z, q.w};
        #pragma unroll
        for (int j = 0; j < 4; ++j) {
            __hip_bfloat162 h = *(__hip_bfloat162*)&wds[j];
            float f0 = __low2float(h), f1 = __high2float(h);
            s[2 * j] += f0;      s2[2 * j] += f0 * f0;
            s[2 * j + 1] += f1;  s2[2 * j + 1] += f1 * f1;
        }
    }
    __shared__ float sh[2][256][8];
    #pragma unroll
    for (int j = 0; j < 8; ++j) { sh[0][threadIdx.x][j] = s[j]; sh[1][threadIdx.x][j] = s2[j]; }
    __syncthreads();
    if (threadIdx.x < C_CH) {
        const int c = threadIdx.x;
        float ts = 0.f, t2 = 0.f;
        #pragma unroll
        for (int q = 0; q < 32; ++q) {
            ts += sh[0][8 * q + (c >> 3)][c & 7];
            t2 += sh[1][8 * q + (c >> 3)][c & 7];
        }
        unsafeAtomicAdd(&stats[c], ts);
        unsafeAtomicAdd(&stats[C_CH + c], t2);
    }
}

// ---------------------------------------------------------------------------
// Kernel 3: y = relu((ws - mean) * rsqrt(var+eps) * gamma + beta).
// ---------------------------------------------------------------------------
__global__ __launch_bounds__(256) void bn_apply(
    const __hip_bfloat16* __restrict__ ws, const float* __restrict__ stats,
    const float* __restrict__ gamma, const float* __restrict__ beta,
    float* __restrict__ out)
{
    const float inv_n = 1.0f / (float)N_OUT_PTS;
    const int c0 = 8 * (threadIdx.x & 7);
    float sc[8], bs[8];
    #pragma unroll
    for (int j = 0; j < 8; ++j) {
        int c = c0 + j;
        float mean = stats[c] * inv_n;
        float var = stats[C_CH + c] * inv_n - mean * mean;
        float s = gamma[c] * rsqrtf(var + BN_EPS);
        sc[j] = s;
        bs[j] = beta[c] - mean * s;
    }
    const uint4* in = (const uint4*)ws;
    float4* o4 = (float4*)out;
    const size_t n = (size_t)N_OUT_PTS * C_CH / 8;
    const size_t stride = (size_t)gridDim.x * blockDim.x;
    for (size_t i = (size_t)blockIdx.x * blockDim.x + threadIdx.x; i < n; i += stride) {
        uint4 q = in[i];
        unsigned wds[4] = {q.x, q.y, q.z, q.w};
        float f[8];
        #pragma unroll
        for (int j = 0; j < 4; ++j) {
            __hip_bfloat162 h = *(__hip_bfloat162*)&wds[j];
            f[2 * j] = __low2float(h);
            f[2 * j + 1] = __high2float(h);
        }
        float4 r0, r1;
        r0.x = fmaxf(fmaf(f[0], sc[0], bs[0]), 0.f);
        r0.y = fmaxf(fmaf(f[1], sc[1], bs[1]), 0.f);
        r0.z = fmaxf(fmaf(f[2], sc[2], bs[2]), 0.f);
        r0.w = fmaxf(fmaf(f[3], sc[3], bs[3]), 0.f);
        r1.x = fmaxf(fmaf(f[4], sc[4], bs[4]), 0.f);
        r1.y = fmaxf(fmaf(f[5], sc[5], bs[5]), 0.f);
        r1.z = fmaxf(fmaf(f[6], sc[6], bs[6]), 0.f);
        r1.w = fmaxf(fmaf(f[7], sc[7], bs[7]), 0.f);
        o4[2 * i] = r0;
        o4[2 * i + 1] = r1;
    }
}

extern "C" void kernel_launch(void* const* d_in, const int* in_sizes, int n_in,
                              void* d_out, int out_size, void* d_ws, size_t ws_size,
                              hipStream_t stream) {
    const float* x      = (const float*)d_in[0];
    const float* W      = (const float*)d_in[1];
    const float* gamma  = (const float*)d_in[2];
    const float* beta   = (const float*)d_in[3];
    const int*   in_idx = (const int*)d_in[4];
    const int*   out_idx= (const int*)d_in[5];
    float* out = (float*)d_out;

    __hip_bfloat16* out_ws = (__hip_bfloat16*)d_ws;       // N_OUT*64 bf16 accumulator
    const size_t acc_elems = (size_t)N_OUT_PTS * C_CH;
    float* stats = (float*)((char*)d_ws + acc_elems * sizeof(__hip_bfloat16));

    const size_t clear_bytes = acc_elems * sizeof(__hip_bfloat16) + 2 * C_CH * sizeof(float);
    (void)hipMemsetAsync(d_ws, 0, clear_bytes, stream);

    dim3 g1(BLK_X, K_OFF);   // (125, 27), block = 128
    scatter_gemm<<<g1, WAVES_PB * 64, 0, stream>>>(x, W, in_idx, out_idx, out_ws);

    bn_stats<<<2048, 256, 0, stream>>>(out_ws, stats);

    bn_apply<<<2048, 256, 0, stream>>>(out_ws, stats, gamma, beta, out);
}